// Round 1
// baseline (102.301 us; speedup 1.0000x reference)
//
#include <hip/hip_runtime.h>
#include <hip/hip_bf16.h>
#include <stdint.h>

typedef float f4 __attribute__((ext_vector_type(4)));
typedef short bf8 __attribute__((ext_vector_type(8)));
typedef unsigned short ushort_t;

#define SDIM 1024
#define DDIM 64
#define NBH  32
#define KM   4
#define BM   64
#define BN   64

__device__ __forceinline__ unsigned short f2bf(float f) {
  uint32_t u = __builtin_bit_cast(uint32_t, f);
  u += 0x7fffu + ((u >> 16) & 1u);   // RNE; inputs are finite, non-NaN
  return (unsigned short)(u >> 16);
}

// ---------- pre-pass: fp32 -> bf16 (with scale) ----------
__global__ __launch_bounds__(256) void conv_bf16(const float* __restrict__ src,
                                                 unsigned short* __restrict__ dst,
                                                 float scale, int n8) {
  int i = blockIdx.x * 256 + threadIdx.x;
  if (i >= n8) return;
  int base = i * 8;
  f4 a = *(const f4*)(src + base);
  f4 b = *(const f4*)(src + base + 4);
  bf8 o;
  o[0] = (short)f2bf(a[0] * scale); o[1] = (short)f2bf(a[1] * scale);
  o[2] = (short)f2bf(a[2] * scale); o[3] = (short)f2bf(a[3] * scale);
  o[4] = (short)f2bf(b[0] * scale); o[5] = (short)f2bf(b[1] * scale);
  o[6] = (short)f2bf(b[2] * scale); o[7] = (short)f2bf(b[3] * scale);
  *(bf8*)(dst + base) = o;
}

// ---------- pre-pass: v [bh][s][d] fp32 -> vt [bh][d][s] bf16 ----------
__global__ __launch_bounds__(256) void transp_v(const float* __restrict__ v,
                                                unsigned short* __restrict__ vt) {
  __shared__ float tv[64][65];   // +1 pad
  int bh = blockIdx.x >> 4;
  int s0 = (blockIdx.x & 15) * 64;
  int t = threadIdx.x;
  int sr = t >> 2, c0 = (t & 3) * 16;
  const float* vp = v + ((size_t)(bh * SDIM) + s0 + sr) * DDIM + c0;
#pragma unroll
  for (int i = 0; i < 4; ++i) {
    f4 x = *(const f4*)(vp + 4 * i);
#pragma unroll
    for (int j = 0; j < 4; ++j) tv[sr][c0 + 4 * i + j] = x[j];
  }
  __syncthreads();
  int d = t >> 2, sc0 = (t & 3) * 16;
  unsigned short tmp[16];
#pragma unroll
  for (int i = 0; i < 16; ++i) tmp[i] = f2bf(tv[sc0 + i][d]);
  unsigned short* op = vt + ((size_t)(bh * DDIM) + d) * SDIM + s0 + sc0;
  bf8 o0, o1;
#pragma unroll
  for (int j = 0; j < 8; ++j) { o0[j] = (short)tmp[j]; o1[j] = (short)tmp[j + 8]; }
  *(bf8*)(op) = o0;
  *(bf8*)(op + 8) = o1;
}

// ---------- pre-pass: fp32 binary mask -> bit words ----------
__global__ __launch_bounds__(256) void mask_to_bits(const float* __restrict__ mask,
                                                    uint32_t* __restrict__ mbits) {
  int gid = blockIdx.x * 256 + threadIdx.x;
  float m = mask[gid];
  unsigned long long bal = __ballot(m > 0.5f);
  int lane = threadIdx.x & 63;
  if (lane == 0)       mbits[gid >> 5] = (uint32_t)bal;
  else if (lane == 32) mbits[gid >> 5] = (uint32_t)(bal >> 32);
}

// ---------- fused attention ----------
// block = 256 thr (4 waves); block handles (bh, 64-row q tile); wave w handles mask w.
// LDS tiles XOR-swizzled: byte ^= ((row&7)<<4) (16B-chunk granularity).
__global__ __launch_bounds__(256, 2) void attn_main(
    const unsigned short* __restrict__ qb, const unsigned short* __restrict__ kb,
    const unsigned short* __restrict__ vtg, const uint32_t* __restrict__ mbits,
    float* __restrict__ outO, float* __restrict__ attn) {
  __shared__ __align__(16) unsigned short q_s[BM * DDIM];  // [row][d]
  __shared__ __align__(16) unsigned short k_s[BN * DDIM];  // [col][d]
  __shared__ __align__(16) unsigned short v_s[DDIM * BN];  // [d][kk]
  __shared__ __align__(16) float          s_s[BM * BN];    // [row][col] fp32

  const int tid = threadIdx.x;
  const int l   = tid & 63;
  const int w   = tid >> 6;          // wave id == mask id
  const int bh  = blockIdx.x >> 4;
  const int r0  = (blockIdx.x & 15) * BM;
  const int l16 = l & 15;
  const int lg  = l >> 4;            // 0..3 (k-group)

  // stage q once (already scaled by 1/8, bf16)
  {
    int rr = tid >> 3, d0 = (tid & 7) * 8;
#pragma unroll
    for (int p = 0; p < 2; ++p) {
      int r = rr + 32 * p;
      bf8 x = *(const bf8*)(qb + ((size_t)(bh * SDIM) + r0 + r) * DDIM + d0);
      *(bf8*)((char*)q_s + (((r * DDIM + d0) * 2) ^ ((r & 7) << 4))) = x;
    }
  }

  f4 acc[4][4] = {};   // O accum  (C-layout rows 16mt+4lg+r, col 16nt+l16)
  f4 accl[4]   = {};   // row-sum accum via ones-MFMA (same C-layout)
  bf8 ones;
#pragma unroll
  for (int b = 0; b < 8; ++b) ones[b] = (short)0x3F80;  // bf16 1.0

  for (int ct = 0; ct < SDIM / BN; ++ct) {
    const int c0 = ct * BN;
    __syncthreads();   // prev readers of k_s/v_s/s_s done
    // stage k tile [col][d] and v tile [d][kk]
    {
      int rr = tid >> 3, d0 = (tid & 7) * 8;
#pragma unroll
      for (int p = 0; p < 2; ++p) {
        int r = rr + 32 * p;
        bf8 x = *(const bf8*)(kb + ((size_t)(bh * SDIM) + c0 + r) * DDIM + d0);
        *(bf8*)((char*)k_s + (((r * DDIM + d0) * 2) ^ ((r & 7) << 4))) = x;
        bf8 y = *(const bf8*)(vtg + ((size_t)(bh * DDIM) + r) * SDIM + c0 + d0);
        *(bf8*)((char*)v_s + (((r * BN + d0) * 2) ^ ((r & 7) << 4))) = y;
      }
    }
    __syncthreads();

    // QK^T: wave w computes columns [16w, 16w+16) of the 64x64 S tile
    {
      int kc = 16 * w + l16;
      bf8 b0 = *(const bf8*)((char*)k_s + (((kc * DDIM + lg * 8) * 2)      ^ ((kc & 7) << 4)));
      bf8 b1 = *(const bf8*)((char*)k_s + (((kc * DDIM + lg * 8 + 32) * 2) ^ ((kc & 7) << 4)));
#pragma unroll
      for (int mt = 0; mt < 4; ++mt) {
        int qr = 16 * mt + l16;
        bf8 a0 = *(const bf8*)((char*)q_s + (((qr * DDIM + lg * 8) * 2)      ^ ((qr & 7) << 4)));
        bf8 a1 = *(const bf8*)((char*)q_s + (((qr * DDIM + lg * 8 + 32) * 2) ^ ((qr & 7) << 4)));
        f4 sc = {};
        sc = __builtin_amdgcn_mfma_f32_16x16x32_bf16(a0, b0, sc, 0, 0, 0);
        sc = __builtin_amdgcn_mfma_f32_16x16x32_bf16(a1, b1, sc, 0, 0, 0);
#pragma unroll
        for (int r = 0; r < 4; ++r) {
          int row = 16 * mt + 4 * lg + r;
          int col = 16 * w + l16;
          *(float*)((char*)s_s + (((row * BN + col) * 4) ^ ((row & 7) << 4))) = sc[r];
        }
      }
    }
    __syncthreads();

    // attn output: coalesced 256B bursts per 16-lane group
    {
#pragma unroll
      for (int j = 0; j < 4; ++j) {
        int row = w * 16 + j * 4 + lg;
        int cc = l16 * 4;
        f4 x = *(const f4*)((char*)s_s + (((row * BN + cc) * 4) ^ ((row & 7) << 4)));
        *(f4*)(attn + ((size_t)(bh * SDIM) + r0 + row) * SDIM + c0 + cc) = x;
      }
    }

    // P = mask ? exp(S) : 0  (no max-sub: |S|<~8, fp32-safe); PV + row-sum MFMAs
    {
      bf8 bv[4][2];
#pragma unroll
      for (int nt = 0; nt < 4; ++nt) {
        int dc = 16 * nt + l16;
#pragma unroll
        for (int kt = 0; kt < 2; ++kt)
          bv[nt][kt] = *(const bf8*)((char*)v_s + (((dc * BN + lg * 8 + 32 * kt) * 2) ^ ((dc & 7) << 4)));
      }
#pragma unroll
      for (int mt = 0; mt < 4; ++mt) {
        int row = 16 * mt + l16;   // A-layout row
        const uint32_t* mrow = mbits + ((size_t)(w * SDIM) + r0 + row) * 32 + ct * 2;
        bf8 af[2];
#pragma unroll
        for (int kt = 0; kt < 2; ++kt) {
          int cb = lg * 8 + 32 * kt;
          f4 s0 = *(const f4*)((char*)s_s + (((row * BN + cb) * 4)       ^ ((row & 7) << 4)));
          f4 s1 = *(const f4*)((char*)s_s + (((row * BN + cb + 4) * 4)   ^ ((row & 7) << 4)));
          uint32_t bits = (mrow[kt] >> (lg * 8)) & 0xffu;
          bf8 a;
#pragma unroll
          for (int b = 0; b < 8; ++b) {
            float sv = (b < 4) ? s0[b] : s1[b - 4];
            float pv = ((bits >> b) & 1u) ? __expf(sv) : 0.0f;
            a[b] = (short)f2bf(pv);
          }
          af[kt] = a;
        }
        accl[mt] = __builtin_amdgcn_mfma_f32_16x16x32_bf16(af[0], ones, accl[mt], 0, 0, 0);
        accl[mt] = __builtin_amdgcn_mfma_f32_16x16x32_bf16(af[1], ones, accl[mt], 0, 0, 0);
#pragma unroll
        for (int nt = 0; nt < 4; ++nt) {
          acc[mt][nt] = __builtin_amdgcn_mfma_f32_16x16x32_bf16(af[0], bv[nt][0], acc[mt][nt], 0, 0, 0);
          acc[mt][nt] = __builtin_amdgcn_mfma_f32_16x16x32_bf16(af[1], bv[nt][1], acc[mt][nt], 0, 0, 0);
        }
      }
    }
  }

  // epilogue: O /= l ; accl has the row sum replicated in every C column
#pragma unroll
  for (int mt = 0; mt < 4; ++mt) {
#pragma unroll
    for (int r = 0; r < 4; ++r) {
      float inv = 1.0f / accl[mt][r];
      int row = 16 * mt + 4 * lg + r;
#pragma unroll
      for (int nt = 0; nt < 4; ++nt) {
        int dc = 16 * nt + l16;
        outO[(((size_t)(w * NBH + bh)) * SDIM + r0 + row) * DDIM + dc] = acc[mt][nt][r] * inv;
      }
    }
  }
}

extern "C" void kernel_launch(void* const* d_in, const int* in_sizes, int n_in,
                              void* d_out, int out_size, void* d_ws, size_t ws_size,
                              hipStream_t stream) {
  (void)in_sizes; (void)n_in; (void)out_size; (void)ws_size;
  const float* q    = (const float*)d_in[0];
  const float* k    = (const float*)d_in[1];
  const float* v    = (const float*)d_in[2];
  const float* mask = (const float*)d_in[3];
  float* outO = (float*)d_out;
  float* attn = (float*)d_out + (size_t)KM * NBH * SDIM * DDIM;  // 8,388,608

  char* ws = (char*)d_ws;
  unsigned short* qb = (unsigned short*)ws;                    // 4 MB
  unsigned short* kb = (unsigned short*)(ws + (4u << 20));     // 4 MB
  unsigned short* vt = (unsigned short*)(ws + (8u << 20));     // 4 MB
  uint32_t*       mb = (uint32_t*)(ws + (12u << 20));          // 512 KB

  const int n  = NBH * SDIM * DDIM;   // 2,097,152 per tensor
  const int n8 = n / 8;               // 262,144
  conv_bf16<<<n8 / 256, 256, 0, stream>>>(q, qb, 0.125f, n8);
  conv_bf16<<<n8 / 256, 256, 0, stream>>>(k, kb, 1.0f, n8);
  transp_v<<<NBH * 16, 256, 0, stream>>>(v, vt);
  mask_to_bits<<<(KM * SDIM * SDIM) / 256, 256, 0, stream>>>(mask, mb);
  attn_main<<<NBH * 16, 256, 0, stream>>>(qb, kb, vt, mb, outO, attn);
}

// Round 2
// 61.653 us; speedup vs baseline: 1.6593x; 1.6593x over previous
//
#include <hip/hip_runtime.h>
#include <hip/hip_bf16.h>
#include <stdint.h>

typedef float f4 __attribute__((ext_vector_type(4)));
typedef short bf8 __attribute__((ext_vector_type(8)));
typedef uint32_t u4 __attribute__((ext_vector_type(4)));

#define SDIM 1024
#define DDIM 64
#define NBH  32
#define KM   4
#define NT   16   // SDIM / 64

__device__ __forceinline__ unsigned short f2bf(float f) {
  uint32_t u = __builtin_bit_cast(uint32_t, f);
  u += 0x7fffu + ((u >> 16) & 1u);   // RNE; finite inputs
  return (unsigned short)(u >> 16);
}

// async 16B global->LDS (lane-linear dest; swizzle via pre-swizzled SOURCE addr)
#define GLOAD16(gsrc, ldst)                                                  \
  __builtin_amdgcn_global_load_lds(                                          \
      (const __attribute__((address_space(1))) unsigned int*)(gsrc),         \
      (__attribute__((address_space(3))) unsigned int*)(ldst), 16, 0, 0)

// swizzled LDS read: [row][64] bf16 tile, byte ^= (row&7)<<4
__device__ __forceinline__ bf8 lds_ld(const unsigned short* base, int row, int e0) {
  return *(const bf8*)((const char*)base + (((row * 64 + e0) * 2) ^ ((row & 7) << 4)));
}

// ---------- pre-pass: q,k fp32 -> bf16 (q scaled by 1/8) ----------
__global__ __launch_bounds__(256) void conv_qk(const float* __restrict__ q,
                                               const float* __restrict__ k,
                                               unsigned short* __restrict__ qb,
                                               unsigned short* __restrict__ kb, int n8) {
  int i = blockIdx.x * 256 + threadIdx.x;
  const float* src = q;
  unsigned short* dst = qb;
  float scale = 0.125f;
  int j = i;
  if (i >= n8) { src = k; dst = kb; scale = 1.0f; j = i - n8; }
  int base = j * 8;
  f4 a = *(const f4*)(src + base);
  f4 b = *(const f4*)(src + base + 4);
  bf8 o;
  o[0] = (short)f2bf(a[0] * scale); o[1] = (short)f2bf(a[1] * scale);
  o[2] = (short)f2bf(a[2] * scale); o[3] = (short)f2bf(a[3] * scale);
  o[4] = (short)f2bf(b[0] * scale); o[5] = (short)f2bf(b[1] * scale);
  o[6] = (short)f2bf(b[2] * scale); o[7] = (short)f2bf(b[3] * scale);
  *(bf8*)(dst + base) = o;
}

// ---------- pre-pass: v [bh][s][d] fp32 -> vt [bh][d][s] bf16 ----------
__global__ __launch_bounds__(256) void transp_v(const float* __restrict__ v,
                                                unsigned short* __restrict__ vt) {
  __shared__ float tv[64][65];
  int bh = blockIdx.x >> 4;
  int s0 = (blockIdx.x & 15) * 64;
  int t = threadIdx.x;
  int sr = t >> 2, c0 = (t & 3) * 16;
  const float* vp = v + ((size_t)(bh * SDIM) + s0 + sr) * DDIM + c0;
#pragma unroll
  for (int i = 0; i < 4; ++i) {
    f4 x = *(const f4*)(vp + 4 * i);
#pragma unroll
    for (int j = 0; j < 4; ++j) tv[sr][c0 + 4 * i + j] = x[j];
  }
  __syncthreads();
  int d = t >> 2, sc0 = (t & 3) * 16;
  unsigned short tmp[16];
#pragma unroll
  for (int i = 0; i < 16; ++i) tmp[i] = f2bf(tv[sc0 + i][d]);
  unsigned short* op = vt + ((size_t)(bh * DDIM) + d) * SDIM + s0 + sc0;
  bf8 o0, o1;
#pragma unroll
  for (int j = 0; j < 8; ++j) { o0[j] = (short)tmp[j]; o1[j] = (short)tmp[j + 8]; }
  *(bf8*)(op) = o0;
  *(bf8*)(op + 8) = o1;
}

// ---------- pre-pass: fp32 mask -> transposed bit words mb2[m][word][row] ----------
__global__ __launch_bounds__(256) void mask_to_bits(const float* __restrict__ mask,
                                                    uint32_t* __restrict__ mb2) {
  int gid = blockIdx.x * 256 + threadIdx.x;
  float mv = mask[gid];
  unsigned long long bal = __ballot(mv > 0.5f);
  int lane = threadIdx.x & 63;
  int m = gid >> 20;
  int r = (gid >> 10) & 1023;
  int c = gid & 1023;
  if (lane == 0)       mb2[m * 32768 + (c >> 5) * 1024 + r] = (uint32_t)bal;
  else if (lane == 32) mb2[m * 32768 + (c >> 5) * 1024 + r] = (uint32_t)(bal >> 32);
}

// ---------- fused attention ----------
// 512 thr (8 waves). Wave w: QK owns S-frags (rows 16*(w>>1), col-half w&1);
// PV: mask m=w>>1, row-half h=w&1 (rows 32h..32h+31).
// exp computed ONCE into shared bf16 E tile; masks applied as packed bit-AND.
// k/v double-buffered via async global_load_lds (pre-swizzled source).
__global__ __launch_bounds__(512, 4) void attn_main(
    const unsigned short* __restrict__ qb, const unsigned short* __restrict__ kb,
    const unsigned short* __restrict__ vtg, const uint32_t* __restrict__ mb2,
    float* __restrict__ outO, float* __restrict__ attn) {
  __shared__ __align__(16) unsigned short q_s[64 * 64];
  __shared__ __align__(16) unsigned short k_s[2][64 * 64];
  __shared__ __align__(16) unsigned short v_s[2][64 * 64];
  __shared__ __align__(16) unsigned short e_s[64 * 64];

  const int tid = threadIdx.x;
  const int l   = tid & 63;
  const int w   = tid >> 6;      // 0..7
  const int m   = w >> 1;        // mask id (also QK row-tile)
  const int h   = w & 1;         // PV row half (also QK col half)
  const int l16 = l & 15;
  const int lg  = l >> 4;

  // XCD-bijective swizzle (512 % 8 == 0): 64 consecutive logical blocks per XCD
  int bid = (int)blockIdx.x;
  bid = (bid & 7) * 64 + (bid >> 3);
  const int bh = bid >> 4;
  const int r0 = (bid & 15) * 64;

  // staging: lane-linear LDS dest (tid*16B), source d-chunk = chunk ^ (row&7)
  const int srow = tid >> 3;
  const int sd   = ((tid & 7) ^ (srow & 7)) << 3;
  const unsigned short* qsrc = qb  + ((size_t)(bh * SDIM) + r0 + srow) * DDIM + sd;
  const unsigned short* ksrc = kb  + ((size_t)(bh * SDIM) + srow) * DDIM + sd;       // +ct*4096
  const unsigned short* vsrc = vtg + ((size_t)(bh * DDIM) + srow) * SDIM + sd;       // +ct*64

  GLOAD16(qsrc, &q_s[tid * 8]);
  GLOAD16(ksrc, &k_s[0][tid * 8]);
  GLOAD16(vsrc, &v_s[0][tid * 8]);

  f4 acc[2][4] = {};
  f4 accl[2]   = {};
  bf8 ones;
#pragma unroll
  for (int b = 0; b < 8; ++b) ones[b] = (short)0x3F80;

  const uint32_t* mbase = mb2 + m * 32768 + r0 + l16;

  for (int ct = 0; ct < NT; ++ct) {
    const int cur = ct & 1;
    __syncthreads();   // B1: prev PV done (e_s free), staged buf[cur] drained

    // early mask-word loads (L2-hot, used in PV after B2)
    uint32_t mdw[2][2];
#pragma unroll
    for (int mt2 = 0; mt2 < 2; ++mt2)
#pragma unroll
      for (int kt = 0; kt < 2; ++kt)
        mdw[mt2][kt] = mbase[(ct * 2 + kt) * 1024 + 16 * (2 * h + mt2)];

    // ---- QK: this wave's 2 frags (rows 16m.., cols 32h+16j..) ----
    {
      const int qr  = 16 * m + l16;
      const int kc0 = 32 * h + l16;
      bf8 a0  = lds_ld(q_s, qr, lg * 8);
      bf8 a1  = lds_ld(q_s, qr, lg * 8 + 32);
      bf8 b00 = lds_ld(k_s[cur], kc0,      lg * 8);
      bf8 b01 = lds_ld(k_s[cur], kc0,      lg * 8 + 32);
      bf8 b10 = lds_ld(k_s[cur], kc0 + 16, lg * 8);
      bf8 b11 = lds_ld(k_s[cur], kc0 + 16, lg * 8 + 32);
      f4 s0 = {}, s1 = {};
      s0 = __builtin_amdgcn_mfma_f32_16x16x32_bf16(a0, b00, s0, 0, 0, 0);
      s0 = __builtin_amdgcn_mfma_f32_16x16x32_bf16(a1, b01, s0, 0, 0, 0);
      s1 = __builtin_amdgcn_mfma_f32_16x16x32_bf16(a0, b10, s1, 0, 0, 0);
      s1 = __builtin_amdgcn_mfma_f32_16x16x32_bf16(a1, b11, s1, 0, 0, 0);

      // attn direct store + shared E (bf16) write
      float* arow = attn + ((size_t)(bh * SDIM) + r0 + 16 * m + 4 * lg) * SDIM
                    + ct * 64 + 32 * h + l16;
#pragma unroll
      for (int j = 0; j < 2; ++j) {
        f4 sv = j ? s1 : s0;
#pragma unroll
        for (int r = 0; r < 4; ++r) {
          arow[(size_t)r * SDIM + 16 * j] = sv[r];
          int row = 16 * m + 4 * lg + r;
          int col = 32 * h + 16 * j + l16;
          *(unsigned short*)((char*)e_s + (((row * 64 + col) * 2) ^ ((row & 7) << 4)))
              = f2bf(__expf(sv[r]));
        }
      }
    }
    __syncthreads();   // B2: E tile visible

    // stage next k/v tile (async; latency hides under PV, drains at next B1)
    if (ct + 1 < NT) {
      const int nxt = cur ^ 1;
      GLOAD16(ksrc + (size_t)(ct + 1) * 4096, &k_s[nxt][tid * 8]);
      GLOAD16(vsrc + (size_t)(ct + 1) * 64,   &v_s[nxt][tid * 8]);
    }

    // ---- PV: mask m, rows 32h..32h+31 ----
    {
      bf8 af[2][2];
#pragma unroll
      for (int mt2 = 0; mt2 < 2; ++mt2) {
        const int row = 16 * (2 * h + mt2) + l16;
#pragma unroll
        for (int kt = 0; kt < 2; ++kt) {
          bf8 e = lds_ld(e_s, row, kt * 32 + lg * 8);
          uint32_t bits = (mdw[mt2][kt] >> (lg * 8)) & 0xffu;
          u4 ew = __builtin_bit_cast(u4, e);
#pragma unroll
          for (int d = 0; d < 4; ++d) {
            uint32_t n2 = (bits >> (2 * d)) & 3u;
            uint32_t sp = (n2 * 0x8001u) & 0x00010001u;
            ew[d] &= (sp << 16) - sp;   // {0, 0xFFFF, 0xFFFF0000, 0xFFFFFFFF}
          }
          af[mt2][kt] = __builtin_bit_cast(bf8, ew);
        }
        accl[mt2] = __builtin_amdgcn_mfma_f32_16x16x32_bf16(af[mt2][0], ones, accl[mt2], 0, 0, 0);
        accl[mt2] = __builtin_amdgcn_mfma_f32_16x16x32_bf16(af[mt2][1], ones, accl[mt2], 0, 0, 0);
      }
#pragma unroll
      for (int nt = 0; nt < 4; ++nt) {
        const int dc = 16 * nt + l16;
        bf8 bv0 = lds_ld(v_s[cur], dc, lg * 8);
        bf8 bv1 = lds_ld(v_s[cur], dc, lg * 8 + 32);
#pragma unroll
        for (int mt2 = 0; mt2 < 2; ++mt2) {
          acc[mt2][nt] = __builtin_amdgcn_mfma_f32_16x16x32_bf16(af[mt2][0], bv0, acc[mt2][nt], 0, 0, 0);
          acc[mt2][nt] = __builtin_amdgcn_mfma_f32_16x16x32_bf16(af[mt2][1], bv1, acc[mt2][nt], 0, 0, 0);
        }
      }
    }
  }

  // epilogue: normalize by row-sum (replicated across C cols by ones-MFMA)
#pragma unroll
  for (int mt2 = 0; mt2 < 2; ++mt2) {
#pragma unroll
    for (int r = 0; r < 4; ++r) {
      float inv = 1.0f / accl[mt2][r];
      int row = 16 * (2 * h + mt2) + 4 * lg + r;
      float* orow = outO + (((size_t)(m * NBH + bh)) * SDIM + r0 + row) * DDIM + l16;
#pragma unroll
      for (int nt = 0; nt < 4; ++nt)
        orow[16 * nt] = acc[mt2][nt][r] * inv;
    }
  }
}

extern "C" void kernel_launch(void* const* d_in, const int* in_sizes, int n_in,
                              void* d_out, int out_size, void* d_ws, size_t ws_size,
                              hipStream_t stream) {
  (void)in_sizes; (void)n_in; (void)out_size; (void)ws_size;
  const float* q    = (const float*)d_in[0];
  const float* k    = (const float*)d_in[1];
  const float* v    = (const float*)d_in[2];
  const float* mask = (const float*)d_in[3];
  float* outO = (float*)d_out;
  float* attn = (float*)d_out + (size_t)KM * NBH * SDIM * DDIM;

  char* ws = (char*)d_ws;
  unsigned short* qb = (unsigned short*)ws;                 // 4 MB
  unsigned short* kb = (unsigned short*)(ws + (4u << 20));  // 4 MB
  unsigned short* vt = (unsigned short*)(ws + (8u << 20));  // 4 MB
  uint32_t*       mb = (uint32_t*)(ws + (12u << 20));       // 512 KB

  const int n  = NBH * SDIM * DDIM;   // 2,097,152
  const int n8 = n / 8;               // 262,144
  conv_qk<<<2 * n8 / 256, 256, 0, stream>>>(q, k, qb, kb, n8);
  transp_v<<<NBH * 16, 256, 0, stream>>>(v, vt);
  mask_to_bits<<<(KM * SDIM * SDIM) / 256, 256, 0, stream>>>(mask, mb);
  attn_main<<<NBH * 16, 512, 0, stream>>>(qb, kb, vt, mb, outO, attn);
}

// Round 3
// 57.556 us; speedup vs baseline: 1.7774x; 1.0712x over previous
//
#include <hip/hip_runtime.h>
#include <hip/hip_bf16.h>
#include <stdint.h>

typedef float f4 __attribute__((ext_vector_type(4)));
typedef short bf8 __attribute__((ext_vector_type(8)));
typedef uint32_t u4 __attribute__((ext_vector_type(4)));
typedef uint32_t u2 __attribute__((ext_vector_type(2)));

#define SDIM 1024
#define DDIM 64
#define NBH  32
#define KM   4
#define NT   16   // SDIM / 64

#define MB_BLK 16384   // mask: 4*1024*1024 / 256
#define KB_BLK 1024    // k conv: 2,097,152 / 8 / 256
#define VT_BLK 512     // v transpose: 32 bh * 16 tiles

__device__ __forceinline__ unsigned short f2bf(float f) {
  uint32_t u = __builtin_bit_cast(uint32_t, f);
  u += 0x7fffu + ((u >> 16) & 1u);   // RNE; finite inputs
  return (unsigned short)(u >> 16);
}

#define GLOAD16(gsrc, ldst)                                                  \
  __builtin_amdgcn_global_load_lds(                                          \
      (const __attribute__((address_space(1))) unsigned int*)(gsrc),         \
      (__attribute__((address_space(3))) unsigned int*)(ldst), 16, 0, 0)

// swizzled LDS read: [row][64] bf16 tile, byte ^= (row&7)<<4
__device__ __forceinline__ bf8 lds_ld(const unsigned short* base, int row, int e0) {
  return *(const bf8*)((const char*)base + (((row * 64 + e0) * 2) ^ ((row & 7) << 4)));
}

// ---------- fused prepass: mask->bits | k fp32->bf16 | v transpose ----------
__global__ __launch_bounds__(256) void prepass(
    const float* __restrict__ k, const float* __restrict__ v,
    const float* __restrict__ mask, unsigned short* __restrict__ kb,
    unsigned short* __restrict__ vt, uint32_t* __restrict__ mb2) {
  __shared__ float tv[64][65];
  const int b = blockIdx.x;
  const int t = threadIdx.x;
  if (b < MB_BLK) {                       // mask -> transposed bit words [m][word][row]
    int gid = b * 256 + t;
    float mv = mask[gid];
    unsigned long long bal = __ballot(mv > 0.5f);
    int lane = t & 63;
    int m = gid >> 20;
    int r = (gid >> 10) & 1023;
    int c = gid & 1023;
    if (lane == 0)       mb2[m * 32768 + (c >> 5) * 1024 + r] = (uint32_t)bal;
    else if (lane == 32) mb2[m * 32768 + (c >> 5) * 1024 + r] = (uint32_t)(bal >> 32);
  } else if (b < MB_BLK + KB_BLK) {       // k fp32 -> bf16
    int base = ((b - MB_BLK) * 256 + t) * 8;
    f4 a = *(const f4*)(k + base);
    f4 c = *(const f4*)(k + base + 4);
    bf8 o;
    o[0] = (short)f2bf(a[0]); o[1] = (short)f2bf(a[1]);
    o[2] = (short)f2bf(a[2]); o[3] = (short)f2bf(a[3]);
    o[4] = (short)f2bf(c[0]); o[5] = (short)f2bf(c[1]);
    o[6] = (short)f2bf(c[2]); o[7] = (short)f2bf(c[3]);
    *(bf8*)(kb + base) = o;
  } else {                                // v [bh][s][d] -> vt [bh][d][s] bf16
    int vb = b - MB_BLK - KB_BLK;
    int bh = vb >> 4;
    int s0 = (vb & 15) * 64;
    int sr = t >> 2, c0 = (t & 3) * 16;
    const float* vp = v + ((size_t)(bh * SDIM) + s0 + sr) * DDIM + c0;
#pragma unroll
    for (int i = 0; i < 4; ++i) {
      f4 x = *(const f4*)(vp + 4 * i);
#pragma unroll
      for (int j = 0; j < 4; ++j) tv[sr][c0 + 4 * i + j] = x[j];
    }
    __syncthreads();
    int d = t >> 2, sc0 = (t & 3) * 16;
    unsigned short tmp[16];
#pragma unroll
    for (int i = 0; i < 16; ++i) tmp[i] = f2bf(tv[sc0 + i][d]);
    unsigned short* op = vt + ((size_t)(bh * DDIM) + d) * SDIM + s0 + sc0;
    bf8 o0, o1;
#pragma unroll
    for (int j = 0; j < 8; ++j) { o0[j] = (short)tmp[j]; o1[j] = (short)tmp[j + 8]; }
    *(bf8*)(op) = o0;
    *(bf8*)(op + 8) = o1;
  }
}

// ---------- fused attention ----------
// 256 thr (4 waves), 32 q-rows per block, grid 1024 (4 blocks/CU).
// Wave w: PV mask = w. QK (swapped: mfma(K,Q) -> lane holds q-row l16, 4 consec k-cols
// per reg): wave computes q-row-tile (w&1), k-col-half (w>>1).
__global__ __launch_bounds__(256, 4) void attn_main(
    const float* __restrict__ qf, const unsigned short* __restrict__ kb,
    const unsigned short* __restrict__ vtg, const uint32_t* __restrict__ mb2,
    float* __restrict__ outO, float* __restrict__ attn) {
  __shared__ __align__(16) unsigned short q_s[32 * 64];     // 4 KB
  __shared__ __align__(16) unsigned short k_s[2][64 * 64];  // 16 KB
  __shared__ __align__(16) unsigned short v_s[2][64 * 64];  // 16 KB
  __shared__ __align__(16) unsigned short e_s[32 * 64];     // 4 KB

  const int tid = threadIdx.x;
  const int l   = tid & 63;
  const int w   = tid >> 6;      // 0..3 = mask id
  const int l16 = l & 15;
  const int lg  = l >> 4;
  const int wh  = w & 1;         // q-row tile (QK)
  const int wc  = w >> 1;        // k-col 32-half (QK)

  int bid = (int)blockIdx.x;
  bid = (bid & 7) * 128 + (bid >> 3);   // XCD-bijective (1024 % 8 == 0)
  const int bh = bid >> 5;
  const int r0 = (bid & 31) * 32;

  // staging addresses: lane-linear LDS dest; source chunk pre-swizzled
  const int srow = tid >> 3;
  const int sd   = ((tid & 7) ^ (srow & 7)) << 3;   // (srow+32)&7 == srow&7
  const unsigned short* ksrc0 = kb  + ((size_t)(bh * SDIM) + srow) * DDIM + sd;
  const unsigned short* ksrc1 = kb  + ((size_t)(bh * SDIM) + srow + 32) * DDIM + sd;
  const unsigned short* vsrc0 = vtg + ((size_t)(bh * DDIM) + srow) * SDIM + sd;
  const unsigned short* vsrc1 = vtg + ((size_t)(bh * DDIM) + srow + 32) * SDIM + sd;

  GLOAD16(ksrc0, &k_s[0][tid * 8]);
  GLOAD16(ksrc1, &k_s[0][(tid + 256) * 8]);
  GLOAD16(vsrc0, &v_s[0][tid * 8]);
  GLOAD16(vsrc1, &v_s[0][(tid + 256) * 8]);

  // q: fp32 -> bf16*0.125, reg-staged once (overlaps the async loads above)
  {
    int row = tid >> 3, d0 = (tid & 7) * 8;
    const float* qp = qf + ((size_t)(bh * SDIM) + r0 + row) * DDIM + d0;
    f4 a = *(const f4*)qp;
    f4 c = *(const f4*)(qp + 4);
    bf8 o;
    o[0] = (short)f2bf(a[0] * 0.125f); o[1] = (short)f2bf(a[1] * 0.125f);
    o[2] = (short)f2bf(a[2] * 0.125f); o[3] = (short)f2bf(a[3] * 0.125f);
    o[4] = (short)f2bf(c[0] * 0.125f); o[5] = (short)f2bf(c[1] * 0.125f);
    o[6] = (short)f2bf(c[2] * 0.125f); o[7] = (short)f2bf(c[3] * 0.125f);
    *(bf8*)((char*)q_s + (((row * 64 + d0) * 2) ^ ((row & 7) << 4))) = o;
  }

  f4 acc[2][4] = {};
  f4 accl[2]   = {};
  bf8 ones;
#pragma unroll
  for (int b = 0; b < 8; ++b) ones[b] = (short)0x3F80;

  const uint32_t* mbase = mb2 + w * 32768 + r0 + l16;

  __syncthreads();   // q_s written, buf0 staged (vmcnt+lgkm drained)

  for (int ct = 0; ct < NT; ++ct) {
    const int cur = ct & 1;

    // mask words (used in PV)
    uint32_t mdw[2][2];
#pragma unroll
    for (int mt2 = 0; mt2 < 2; ++mt2)
#pragma unroll
      for (int kt = 0; kt < 2; ++kt)
        mdw[mt2][kt] = mbase[(ct * 2 + kt) * 1024 + 16 * mt2];

    // ---- QK (swapped): S[qrow=l16+16wh][kcol = 32wc+16j+4lg+r] ----
    {
      const int qr = 16 * wh + l16;
      bf8 bq0 = lds_ld(q_s, qr, lg * 8);
      bf8 bq1 = lds_ld(q_s, qr, lg * 8 + 32);
      f4 s[2];
#pragma unroll
      for (int j = 0; j < 2; ++j) {
        const int kc = 32 * wc + 16 * j + l16;
        bf8 ak0 = lds_ld(k_s[cur], kc, lg * 8);
        bf8 ak1 = lds_ld(k_s[cur], kc, lg * 8 + 32);
        f4 sv = {};
        sv = __builtin_amdgcn_mfma_f32_16x16x32_bf16(ak0, bq0, sv, 0, 0, 0);
        sv = __builtin_amdgcn_mfma_f32_16x16x32_bf16(ak1, bq1, sv, 0, 0, 0);
        s[j] = sv;
      }
      // attn: one f4 store per frag (lane has 4 consecutive k-cols)
      float* arow = attn + ((size_t)(bh * SDIM) + r0 + 16 * wh + l16) * SDIM
                    + ct * 64 + 32 * wc + 4 * lg;
      *(f4*)(arow)      = s[0];
      *(f4*)(arow + 16) = s[1];
      // E tile: exp + pack -> one 8B ds_write per frag
      const int erow = 16 * wh + l16;
#pragma unroll
      for (int j = 0; j < 2; ++j) {
        u2 ev;
        ev[0] = (uint32_t)f2bf(__expf(s[j][0])) | ((uint32_t)f2bf(__expf(s[j][1])) << 16);
        ev[1] = (uint32_t)f2bf(__expf(s[j][2])) | ((uint32_t)f2bf(__expf(s[j][3])) << 16);
        int col = 32 * wc + 16 * j + 4 * lg;
        *(u2*)((char*)e_s + (((erow * 64 + col) * 2) ^ ((erow & 7) << 4))) = ev;
      }
    }
    __syncthreads();   // B2: E visible

    // stage next k/v (drains at end-of-body barrier; PV covers latency)
    if (ct + 1 < NT) {
      const int nxt = cur ^ 1;
      GLOAD16(ksrc0 + (size_t)(ct + 1) * 4096, &k_s[nxt][tid * 8]);
      GLOAD16(ksrc1 + (size_t)(ct + 1) * 4096, &k_s[nxt][(tid + 256) * 8]);
      GLOAD16(vsrc0 + (size_t)(ct + 1) * 64,   &v_s[nxt][tid * 8]);
      GLOAD16(vsrc1 + (size_t)(ct + 1) * 64,   &v_s[nxt][(tid + 256) * 8]);
    }

    // ---- PV: mask w, rows 0..31 ----
    {
      bf8 af[2][2];
#pragma unroll
      for (int mt2 = 0; mt2 < 2; ++mt2) {
        const int row = 16 * mt2 + l16;
#pragma unroll
        for (int kt = 0; kt < 2; ++kt) {
          bf8 e = lds_ld(e_s, row, kt * 32 + lg * 8);
          uint32_t bits = (mdw[mt2][kt] >> (lg * 8)) & 0xffu;
          u4 ew = __builtin_bit_cast(u4, e);
#pragma unroll
          for (int d = 0; d < 4; ++d) {
            uint32_t n2 = (bits >> (2 * d)) & 3u;
            uint32_t sp = (n2 * 0x8001u) & 0x00010001u;
            ew[d] &= (sp << 16) - sp;
          }
          af[mt2][kt] = __builtin_bit_cast(bf8, ew);
        }
        accl[mt2] = __builtin_amdgcn_mfma_f32_16x16x32_bf16(af[mt2][0], ones, accl[mt2], 0, 0, 0);
        accl[mt2] = __builtin_amdgcn_mfma_f32_16x16x32_bf16(af[mt2][1], ones, accl[mt2], 0, 0, 0);
      }
#pragma unroll
      for (int nt = 0; nt < 4; ++nt) {
        const int dc = 16 * nt + l16;
        bf8 bv0 = lds_ld(v_s[cur], dc, lg * 8);
        bf8 bv1 = lds_ld(v_s[cur], dc, lg * 8 + 32);
#pragma unroll
        for (int mt2 = 0; mt2 < 2; ++mt2) {
          acc[mt2][nt] = __builtin_amdgcn_mfma_f32_16x16x32_bf16(af[mt2][0], bv0, acc[mt2][nt], 0, 0, 0);
          acc[mt2][nt] = __builtin_amdgcn_mfma_f32_16x16x32_bf16(af[mt2][1], bv1, acc[mt2][nt], 0, 0, 0);
        }
      }
    }
    __syncthreads();   // B1: PV done (e_s free), next buf staged & drained
  }

  // epilogue: normalize by ones-MFMA row-sum
#pragma unroll
  for (int mt2 = 0; mt2 < 2; ++mt2) {
#pragma unroll
    for (int r = 0; r < 4; ++r) {
      float inv = 1.0f / accl[mt2][r];
      int row = 16 * mt2 + 4 * lg + r;
      float* orow = outO + (((size_t)(w * NBH + bh)) * SDIM + r0 + row) * DDIM + l16;
#pragma unroll
      for (int nt = 0; nt < 4; ++nt)
        orow[16 * nt] = acc[mt2][nt][r] * inv;
    }
  }
}

extern "C" void kernel_launch(void* const* d_in, const int* in_sizes, int n_in,
                              void* d_out, int out_size, void* d_ws, size_t ws_size,
                              hipStream_t stream) {
  (void)in_sizes; (void)n_in; (void)out_size; (void)ws_size;
  const float* q    = (const float*)d_in[0];
  const float* k    = (const float*)d_in[1];
  const float* v    = (const float*)d_in[2];
  const float* mask = (const float*)d_in[3];
  float* outO = (float*)d_out;
  float* attn = (float*)d_out + (size_t)KM * NBH * SDIM * DDIM;

  char* ws = (char*)d_ws;
  unsigned short* kb = (unsigned short*)ws;                 // 4 MB
  unsigned short* vt = (unsigned short*)(ws + (4u << 20));  // 4 MB
  uint32_t*       mb = (uint32_t*)(ws + (8u << 20));        // 512 KB

  prepass<<<MB_BLK + KB_BLK + VT_BLK, 256, 0, stream>>>(k, v, mask, kb, vt, mb);
  attn_main<<<NBH * 32, 256, 0, stream>>>(q, kb, vt, mb, outO, attn);
}